// Round 23
// baseline (383.338 us; speedup 1.0000x reference)
//
#include <hip/hip_runtime.h>
#include <math.h>

#define TDIM 1000
#define BDIM 32
#define VDIM 1000
#define UDIM 100
#define SDIM 201              // 2*U+1
#define EROW 104              // padded pair-row stride (102 used)
#define LN2   0.6931471805599453f
#define PIPE 16               // k_alpha pipeline depth (R20-proven)
#define SCALE_EXP 110         // PROVEN R11-R20
#define NCONS 32              // consumer blocks (one per batch)
#define WMAGIC 0xC0DE0000

typedef __attribute__((ext_vector_type(2))) float f32x2;
typedef __attribute__((ext_vector_type(4))) int   i32x4;

__device__ __forceinline__ float med3c(float x) {
    return __builtin_amdgcn_fmed3f(x, 0.f, 1.f);
}
template <int CTRL>
__device__ __forceinline__ float dppadd(float v) {
    int r = __builtin_amdgcn_update_dpp(
        0, __builtin_bit_cast(int, v), CTRL, 0xf, 0xf, true);
    return v + __builtin_bit_cast(float, r);
}
__device__ __forceinline__ float dpp_shr1_zero(float x) {
    int r = __builtin_amdgcn_update_dpp(
        0, __builtin_bit_cast(int, x), 0x138, 0xf, 0xf, true);
    return __builtin_bit_cast(float, r);
}
template <int CTRL>
__device__ __forceinline__ float dppmax(float v) {
    int r = __builtin_amdgcn_update_dpp(
        0, __builtin_bit_cast(int, v), CTRL, 0xf, 0xf, true);
    return fmaxf(v, __builtin_bit_cast(float, r));
}

// wave0's gate: spin on the LDS watermark (ds_read -> lgkmcnt only; never
// touches wave0's vmcnt, so the counted-vmcnt load pipeline stays intact)
__device__ __forceinline__ void lds_gate(volatile int* wm, int target) {
    for (;;) {
        int v = *wm;
        if (((v >> 16) & 0xFFFF) == 0xC0DE && (v & 0xFFFF) >= target) return;
        __builtin_amdgcn_s_sleep(2);
    }
}

// phase-1 row body -- TEXTUALLY R20's math (bit-identical etab)
__device__ __forceinline__ void p1_row(
    const float* __restrict__ lp, const int* __restrict__ targets,
    const int* __restrict__ tlen, float* __restrict__ etab, int row, int l)
{
    const float* base = lp + (size_t)row * VDIM;
    const float4* p4 = (const float4*)base;
    float4 v0 = p4[l];
    float4 v1 = p4[64 + l];
    float4 v2 = p4[128 + l];
    float4 v3;
    if (l < 58) v3 = p4[192 + l];
    else        v3 = make_float4(-INFINITY, -INFINITY, -INFINITY, -INFINITY);

    float s = __expf(v0.x) + __expf(v0.y) + __expf(v0.z) + __expf(v0.w)
            + __expf(v1.x) + __expf(v1.y) + __expf(v1.z) + __expf(v1.w)
            + __expf(v2.x) + __expf(v2.y) + __expf(v2.z) + __expf(v2.w)
            + __expf(v3.x) + __expf(v3.y) + __expf(v3.z) + __expf(v3.w);
    s = dppadd<0xB1>(s);    // quad_perm xor1
    s = dppadd<0x4E>(s);    // quad_perm xor2
    s = dppadd<0x141>(s);   // row_half_mirror
    s = dppadd<0x140>(s);   // row_mirror
    s += __shfl_xor(s, 16);
    s += __shfl_xor(s, 32);

    const float inv_s = __builtin_amdgcn_rcpf(s);
    const int b = row & (BDIM - 1);
    const int t = row >> 5;
    float* erow = etab + (size_t)(b * TDIM + t) * EROW;
    const int Sb = 2 * tlen[b];
    if (l < 50) {
        const int c0 = targets[b * UDIM + 2 * l];
        const int c1 = targets[b * UDIM + 2 * l + 1];
        const float mk1 = (4 * l + 1 <= Sb) ? 1.f : 0.f;
        const float mk3 = (4 * l + 3 <= Sb) ? 1.f : 0.f;
        float2 o;
        o.x = med3c(__expf(base[c0]) * inv_s) * mk1;
        o.y = med3c(__expf(base[c1]) * inv_s) * mk3;
        *(float2*)(erow + 2 * l) = o;
    } else if (l == 50) {
        float2 o;
        o.x = med3c(__expf(base[0]) * inv_s);   // blank in slot 100
        o.y = 0.f;                              // slot 101 = 0
        *(float2*)(erow + 100) = o;
    }
}

// ---------------------------------------------------------------------------
// Fused producer-consumer kernel.
//  blocks 0..31   : consumers. wave0 = R20 k_alpha (bit-identical math) with
//                   LDS-watermark gates; wave1 = flag poller (own vmcnt);
//                   waves 2,3 exit after the init barrier.
//  blocks 32..1031: producers. block 32+t computes time-slice t (32 rows,
//                   4 waves x 8 rows), then threadfence + flags[t]=1.
// ---------------------------------------------------------------------------
__global__ __launch_bounds__(256, 1) void k_fused(
    const float* __restrict__ lp, const int* __restrict__ targets,
    const int* __restrict__ ilen, const int* __restrict__ tlen,
    float* __restrict__ etab, int* __restrict__ flags,
    float* __restrict__ out)
{
    const int wid = threadIdx.x >> 6;
    const int l = threadIdx.x & 63;

    if (blockIdx.x >= NCONS) {
        // ----------------------- PRODUCER -----------------------
        const int tp = blockIdx.x - NCONS;          // time-slice 0..999
        for (int j = 0; j < 8; ++j)
            p1_row(lp, targets, tlen, etab, tp * BDIM + (wid * 8 + j), l);
        __syncthreads();                            // all 32 rows done
        if (threadIdx.x == 0) {
            __threadfence();                        // agent release: L2 -> coherent point
            __hip_atomic_store(&flags[tp], 1, __ATOMIC_RELEASE,
                               __HIP_MEMORY_SCOPE_AGENT);
        }
        return;
    }

    // ----------------------- CONSUMER -----------------------
    __shared__ int wm_s;
    if (wid == 1 && l == 0) wm_s = WMAGIC;          // watermark V=0 (magic-tagged)
    __syncthreads();                                // poison-proof init
    if (wid >= 2) return;
    volatile int* wmp = &wm_s;

    if (wid == 1) {
        // watchdog: poll flags (this wave's own vmcnt), publish watermark to LDS
        for (int tw = 0; tw < TDIM; ++tw) {
            while (__hip_atomic_load(&flags[tw], __ATOMIC_ACQUIRE,
                                     __HIP_MEMORY_SCOPE_AGENT) == 0)
                __builtin_amdgcn_s_sleep(2);
            if (l == 0) *wmp = WMAGIC | (tw + 1);
        }
        return;
    }

    // wave 0: R20 k_alpha, gated on the LDS watermark
    const int b = blockIdx.x;
    const float* eb = etab + (size_t)b * TDIM * EROW;
    const int eoff = (2 * l <= 100) ? 2 * l : 100;
    const float* plane = eb + eoff;

    f32x2 g = {0.f, 0.f};
    if (l < 50) {
        const int c0 = targets[b * UDIM + 2 * l];
        const int c1 = targets[b * UDIM + 2 * l + 1];
        g.y = (c1 != c0) ? 1.f : 0.f;
        if (l >= 1) g.x = (c0 != targets[b * UDIM + 2 * l - 1]) ? 1.f : 0.f;
    }
    const int u_b = tlen[b];
    const int Sb  = 2 * u_b;

    lds_gate(wmp, 1);                               // t=0 row ready
    f32x2 pr0 = *(const f32x2*)plane;
    const float bl0 = __builtin_bit_cast(float,
        __builtin_amdgcn_readlane(__builtin_bit_cast(int, pr0.x), 50));
    const float F = 1e-30f * 0x1p110f;
    f32x2 E, O;
    E.x = (4 * l     <= Sb) ? F : 0.f;
    E.y = (4 * l + 2 <= Sb) ? F : 0.f;
    O.x = (4 * l + 1 <= Sb) ? F : 0.f;
    O.y = (4 * l + 3 <= Sb) ? F : 0.f;
    if (l == 0) {
        E.x = bl0   * 0x1p110f;
        O.x = pr0.x * 0x1p110f;
    }
    int ksum = -SCALE_EXP;

    int L = ilen[b];
    if (L > TDIM) L = TDIM;

    const unsigned long long ebu = (unsigned long long)eb;
    i32x4 srd;
    srd.x = (int)(ebu & 0xffffffffu);
    srd.y = (int)((ebu >> 32) & 0xffffu);
    srd.z = TDIM * EROW * 4;
    srd.w = 0x00020000;
    const int voff = eoff * 4;
    int so = EROW * 4;

#define STEP(LAB_) {                                                             \
    const float ebv = __builtin_bit_cast(float,                                  \
        __builtin_amdgcn_readlane(__builtin_bit_cast(int, (LAB_).x), 50));       \
    f32x2 ebp; ebp.x = ebv; ebp.y = ebv;                                         \
    const float pP3 = dpp_shr1_zero(O.y);                                        \
    f32x2 sk; sk.x = pP3; sk.y = O.x;                                            \
    const f32x2 T  = E + O;                                                      \
    const f32x2 ev = (E + sk) * ebp;                                             \
    const f32x2 od = (sk * g + T) * (LAB_);                                      \
    E = ev; O = od; }

#define RESCALE() {                                                              \
    float pm = fmaxf(__builtin_amdgcn_fmed3f(                                    \
        fmaxf(E.x, O.x), fmaxf(E.y, O.y), INFINITY), 0x1p-10f);                  \
    pm = dppmax<0xB1>(pm);  pm = dppmax<0x4E>(pm);                               \
    pm = dppmax<0x141>(pm); pm = dppmax<0x140>(pm);                              \
    pm = dppmax<0x142>(pm); pm = dppmax<0x143>(pm);                              \
    const int mb = __builtin_amdgcn_readlane(__builtin_bit_cast(int, pm), 63);   \
    const int ex = (mb >> 23) & 0xff;                                            \
    ksum += ex - (127 + SCALE_EXP);                                              \
    const float sc = __builtin_bit_cast(float, ((254 + SCALE_EXP) - ex) << 23);  \
    f32x2 scv; scv.x = sc; scv.y = sc;                                           \
    E = E * scv; O = O * scv; }

#define ISS(J, OFFP)                                                             \
    asm volatile("buffer_load_dwordx2 %0, %1, %2, %3 offen offset:" OFFP         \
        : "=v"(lab[J]) : "v"(voff), "s"(srd), "s"(so));

#define ISS8(G) \
    ISS((G)+0, "0");    ISS((G)+1, "416");                                       \
    ISS((G)+2, "832");  ISS((G)+3, "1248");                                      \
    ISS((G)+4, "1664"); ISS((G)+5, "2080");                                      \
    ISS((G)+6, "2496"); ISS((G)+7, "2912");

#define WAITG8(J) asm volatile("s_waitcnt vmcnt(8)"                              \
    : "+v"(lab[(J)]),   "+v"(lab[(J)+1]), "+v"(lab[(J)+2]), "+v"(lab[(J)+3]),    \
      "+v"(lab[(J)+4]), "+v"(lab[(J)+5]), "+v"(lab[(J)+6]), "+v"(lab[(J)+7]));

    // gate target VT = 1 + last t of the range this group is about to ISSUE
#define GROUP8(G, VT) {                                                          \
    WAITG8(G);                                                                   \
    STEP(lab[(G)+0]); STEP(lab[(G)+1]);                                          \
    STEP(lab[(G)+2]); STEP(lab[(G)+3]);                                          \
    STEP(lab[(G)+4]); STEP(lab[(G)+5]);                                          \
    STEP(lab[(G)+6]); STEP(lab[(G)+7]);                                          \
    lds_gate(wmp, (VT) < TDIM ? (VT) : TDIM);                                    \
    ISS8(G);                                                                     \
    so += 3328;                                                                  \
    RESCALE(); }

    f32x2 lab[PIPE];
    lds_gate(wmp, 17);                              // rows t=1..16 ready
    ISS8(0);  so += 3328;
    ISS8(8);  so += 3328;

    int t = 1;
    for (; t + PIPE - 1 < L; t += PIPE) {
        GROUP8(0, t + 24);                          // issues t+16..t+23
        GROUP8(8, t + 32);                          // issues t+24..t+31
    }
    asm volatile("s_waitcnt vmcnt(0)" ::: "memory");

    lds_gate(wmp, L < TDIM ? L : TDIM);             // all tail rows ready
    for (; t < L; ++t) {
        f32x2 lb = *(const f32x2*)(plane + (size_t)t * EROW);
        STEP(lb);
        RESCALE();
    }
#undef GROUP8
#undef WAITG8
#undef ISS8
#undef ISS
#undef RESCALE
#undef STEP

    // finalize in-wave via shfl (no LDS / no cross-wave barrier)
    const float lg0 = __builtin_amdgcn_logf(fmaxf(E.x, 1e-38f));
    const float lg1 = __builtin_amdgcn_logf(fmaxf(O.x, 1e-38f));
    const float lg2 = __builtin_amdgcn_logf(fmaxf(E.y, 1e-38f));
    const float lg3 = __builtin_amdgcn_logf(fmaxf(O.y, 1e-38f));
    const int s1 = 2 * u_b - 1, s2 = 2 * u_b;
    const int slot1 = s1 & 3, slot2 = s2 & 3;       // wave-uniform
    const float c1 = (slot1 == 0) ? lg0 : (slot1 == 1) ? lg1
                   : (slot1 == 2) ? lg2 : lg3;
    const float c2 = (slot2 == 0) ? lg0 : (slot2 == 2) ? lg2
                   : (slot2 == 1) ? lg1 : lg3;
    const float x1 = __shfl(c1, s1 >> 2);
    const float x2 = __shfl(c2, s2 >> 2);
    if (l == 0) {
        const float mx = fmaxf(x1, x2), mn = fminf(x1, x2);
        const float lse2 = mx + __builtin_amdgcn_logf(
            1.f + __builtin_amdgcn_exp2f(mn - mx));
        out[b] = -(LN2 * (lse2 + (float)ksum));
    }
}

extern "C" void kernel_launch(void* const* d_in, const int* in_sizes, int n_in,
                              void* d_out, int out_size, void* d_ws, size_t ws_size,
                              hipStream_t stream) {
    const float* lp      = (const float*)d_in[0];   // [T,B,V] f32
    const int*   targets = (const int*)d_in[1];     // [B,U] i32
    const int*   ilen    = (const int*)d_in[2];     // [B] i32
    const int*   tlen    = (const int*)d_in[3];     // [B] i32
    float* out  = (float*)d_out;                    // [B] f32
    float* etab = (float*)d_ws;                     // 13.312 MB
    int* flags  = (int*)((char*)d_ws + (size_t)BDIM * TDIM * EROW * 4); // +4 KB

    hipMemsetAsync(flags, 0, TDIM * sizeof(int), stream);   // re-arm each call
    k_fused<<<NCONS + TDIM, 256, 0, stream>>>(lp, targets, ilen, tlen,
                                              etab, flags, out);
}

// Round 25
// 76.409 us; speedup vs baseline: 5.0169x; 5.0169x over previous
//
#include <hip/hip_runtime.h>
#include <math.h>

#define TDIM 1000
#define BDIM 32
#define VDIM 1000
#define UDIM 100
#define SDIM 201              // 2*U+1
#define EROW 104              // padded pair-row stride (102 used)
#define LN2   0.6931471805599453f
#define PIPE 16               // software-pipeline depth (t-steps of load prefetch)
// Wave max renormalized to 2^110, rescale every 8 steps (PROVEN R11-R20).
#define SCALE_EXP 110

typedef __attribute__((ext_vector_type(2))) float f32x2;
typedef __attribute__((ext_vector_type(4))) float f32x4;   // clang vector: OK for nontemporal builtin
typedef __attribute__((ext_vector_type(4))) int   i32x4;

// med3(x,0,1): 1-instr clamp; NaN input sanitizes to 0.
__device__ __forceinline__ float med3c(float x) {
    return __builtin_amdgcn_fmed3f(x, 0.f, 1.f);
}

// one DPP butterfly level: v += v[xor-partner] (0-fill outside row)
template <int CTRL>
__device__ __forceinline__ float dppadd(float v) {
    int r = __builtin_amdgcn_update_dpp(
        0, __builtin_bit_cast(int, v), CTRL, 0xf, 0xf, true);
    return v + __builtin_bit_cast(float, r);
}

// ---------------------------------------------------------------------------
// Phase 1 (R20 structure; single knob: nt loads for the read-once 128 MB
// stream). R24 compile fix: __builtin_nontemporal_load needs ext_vector_type,
// not HIP's float4 struct -> stream through f32x4 (bit-identical layout).
// Gathers (base[c0], row re-reads) remain NORMAL loads. Math, lane mapping,
// reduce order TEXTUALLY identical -> etab bit-identical.
// ---------------------------------------------------------------------------
__global__ __launch_bounds__(256) void k_lsm_gather(
    const float* __restrict__ lp, const int* __restrict__ targets,
    const int* __restrict__ tlen, float* __restrict__ etab)
{
    const int w = threadIdx.x >> 6, l = threadIdx.x & 63;
    const int row = blockIdx.x * 4 + w;        // row = t*B + b
    const int t = row / BDIM;
    const int b = row - t * BDIM;
    const float* base = lp + (size_t)row * VDIM;
    const f32x4* p4 = (const f32x4*)base;      // 250 vec4 per row

    f32x4 v0 = __builtin_nontemporal_load(&p4[l]);
    f32x4 v1 = __builtin_nontemporal_load(&p4[64 + l]);
    f32x4 v2 = __builtin_nontemporal_load(&p4[128 + l]);
    f32x4 v3;
    if (l < 58) v3 = __builtin_nontemporal_load(&p4[192 + l]);
    else        { v3.x = -INFINITY; v3.y = -INFINITY;
                  v3.z = -INFINITY; v3.w = -INFINITY; }

    float s = __expf(v0.x) + __expf(v0.y) + __expf(v0.z) + __expf(v0.w)
            + __expf(v1.x) + __expf(v1.y) + __expf(v1.z) + __expf(v1.w)
            + __expf(v2.x) + __expf(v2.y) + __expf(v2.z) + __expf(v2.w)
            + __expf(v3.x) + __expf(v3.y) + __expf(v3.z) + __expf(v3.w);
    s = dppadd<0xB1>(s);    // quad_perm xor1
    s = dppadd<0x4E>(s);    // quad_perm xor2
    s = dppadd<0x141>(s);   // row_half_mirror
    s = dppadd<0x140>(s);   // row_mirror
    s += __shfl_xor(s, 16);
    s += __shfl_xor(s, 32);

    const float inv_s = __builtin_amdgcn_rcpf(s);
    float* erow = etab + (size_t)(b * TDIM + t) * EROW;
    const int Sb = 2 * tlen[b];
    if (l < 50) {
        const int c0 = targets[b * UDIM + 2 * l];
        const int c1 = targets[b * UDIM + 2 * l + 1];
        const float mk1 = (4 * l + 1 <= Sb) ? 1.f : 0.f;
        const float mk3 = (4 * l + 3 <= Sb) ? 1.f : 0.f;
        float2 o;
        o.x = med3c(__expf(base[c0]) * inv_s) * mk1;
        o.y = med3c(__expf(base[c1]) * inv_s) * mk3;
        *(float2*)(erow + 2 * l) = o;
    } else if (l == 50) {
        // slot 100 = blank (readlane source); slot 101 = 0 (state-201 odd pad)
        float2 o;
        o.x = med3c(__expf(base[0]) * inv_s);
        o.y = 0.f;
        *(float2*)(erow + 100) = o;
    }
}

// lane l gets lane l-1's value; lane 0 gets 0.0f (additive identity).
__device__ __forceinline__ float dpp_shr1_zero(float x) {
    int r = __builtin_amdgcn_update_dpp(
        0, __builtin_bit_cast(int, x), 0x138, 0xf, 0xf, true);
    return __builtin_bit_cast(float, r);
}

// one butterfly level of a wave64 max-reduce (p >= 0, so 0-fill is identity)
template <int CTRL>
__device__ __forceinline__ float dppmax(float v) {
    int r = __builtin_amdgcn_update_dpp(
        0, __builtin_bit_cast(int, v), CTRL, 0xf, 0xf, true);
    return fmaxf(v, __builtin_bit_cast(float, r));
}

// ---------------------------------------------------------------------------
// Phase 2: byte-identical to R20 (70.0 us champion): 1 wave/CU, PIPE=16,
// readlane blank, packed parity state, cadence-8 exact-pow2 rescale.
// ---------------------------------------------------------------------------
__global__ __launch_bounds__(64, 1) void k_alpha(
    const float* __restrict__ etab, const int* __restrict__ targets,
    const int* __restrict__ ilen, const int* __restrict__ tlen,
    float* __restrict__ out)
{
    const int b = blockIdx.x;
    const int l = threadIdx.x;                 // 0..63
    const float* eb = etab + (size_t)b * TDIM * EROW;
    const int eoff = (2 * l <= 100) ? 2 * l : 100;   // lanes>=50 -> blank pair
    const float* plane = eb + eoff;            // per-lane pair base

    f32x2 g = {0.f, 0.f};                      // skip gates (a1f, a3f)
    if (l < 50) {
        const int c0 = targets[b * UDIM + 2 * l];
        const int c1 = targets[b * UDIM + 2 * l + 1];
        g.y = (c1 != c0) ? 1.f : 0.f;
        if (l >= 1) g.x = (c0 != targets[b * UDIM + 2 * l - 1]) ? 1.f : 0.f;
    }

    const int u_b = tlen[b];
    const int Sb  = 2 * u_b;

    f32x2 pr0 = *(const f32x2*)plane;          // pre-sanitized in phase 1
    const float bl0 = __builtin_bit_cast(float,
        __builtin_amdgcn_readlane(__builtin_bit_cast(int, pr0.x), 50));
    const float F = 1e-30f * 0x1p110f;
    f32x2 E, O;
    E.x = (4 * l     <= Sb) ? F : 0.f;
    E.y = (4 * l + 2 <= Sb) ? F : 0.f;
    O.x = (4 * l + 1 <= Sb) ? F : 0.f;
    O.y = (4 * l + 3 <= Sb) ? F : 0.f;
    if (l == 0) {
        E.x = bl0   * 0x1p110f;                // s=0: blank
        O.x = pr0.x * 0x1p110f;                // s=1: first label
    }
    int ksum = -SCALE_EXP;                     // true log2 = log2(stored) + ksum

    int L = ilen[b];
    if (L > TDIM) L = TDIM;

    const unsigned long long ebu = (unsigned long long)eb;
    i32x4 srd;
    srd.x = (int)(ebu & 0xffffffffu);
    srd.y = (int)((ebu >> 32) & 0xffffu);
    srd.z = TDIM * EROW * 4;
    srd.w = 0x00020000;
    const int voff = eoff * 4;                 // per-lane pair byte offset
    int so = EROW * 4;                         // pair soffset (group base)

#define STEP(LAB_) {                                                             \
    const float ebv = __builtin_bit_cast(float,                                  \
        __builtin_amdgcn_readlane(__builtin_bit_cast(int, (LAB_).x), 50));       \
    f32x2 ebp; ebp.x = ebv; ebp.y = ebv;                                         \
    const float pP3 = dpp_shr1_zero(O.y);                                        \
    f32x2 sk; sk.x = pP3; sk.y = O.x;                                            \
    const f32x2 T  = E + O;                                                      \
    const f32x2 ev = (E + sk) * ebp;                                             \
    const f32x2 od = (sk * g + T) * (LAB_);                                      \
    E = ev; O = od; }

#define RESCALE() {                                                              \
    float pm = fmaxf(__builtin_amdgcn_fmed3f(                                    \
        fmaxf(E.x, O.x), fmaxf(E.y, O.y), INFINITY), 0x1p-10f);                  \
    pm = dppmax<0xB1>(pm);   /* quad_perm xor1  */                               \
    pm = dppmax<0x4E>(pm);   /* quad_perm xor2  */                               \
    pm = dppmax<0x141>(pm);  /* row_half_mirror */                               \
    pm = dppmax<0x140>(pm);  /* row_mirror      */                               \
    pm = dppmax<0x142>(pm);  /* row_bcast15    */                                \
    pm = dppmax<0x143>(pm);  /* row_bcast31    */                                \
    const int mb = __builtin_amdgcn_readlane(__builtin_bit_cast(int, pm), 63);   \
    const int ex = (mb >> 23) & 0xff;                                            \
    ksum += ex - (127 + SCALE_EXP);                                              \
    const float sc = __builtin_bit_cast(float, ((254 + SCALE_EXP) - ex) << 23);  \
    f32x2 scv; scv.x = sc; scv.y = sc;                                           \
    E = E * scv; O = O * scv; }

#define ISS(J, OFFP)                                                             \
    asm volatile("buffer_load_dwordx2 %0, %1, %2, %3 offen offset:" OFFP         \
        : "=v"(lab[J]) : "v"(voff), "s"(srd), "s"(so));

#define ISS8(G) \
    ISS((G)+0, "0");    ISS((G)+1, "416");                                       \
    ISS((G)+2, "832");  ISS((G)+3, "1248");                                      \
    ISS((G)+4, "1664"); ISS((G)+5, "2080");                                      \
    ISS((G)+6, "2496"); ISS((G)+7, "2912");

#define WAITG8(J) asm volatile("s_waitcnt vmcnt(8)"                              \
    : "+v"(lab[(J)]),   "+v"(lab[(J)+1]), "+v"(lab[(J)+2]), "+v"(lab[(J)+3]),    \
      "+v"(lab[(J)+4]), "+v"(lab[(J)+5]), "+v"(lab[(J)+6]), "+v"(lab[(J)+7]));

#define GROUP8(G) {                                                              \
    WAITG8(G);                                                                   \
    STEP(lab[(G)+0]); STEP(lab[(G)+1]);                                          \
    STEP(lab[(G)+2]); STEP(lab[(G)+3]);                                          \
    STEP(lab[(G)+4]); STEP(lab[(G)+5]);                                          \
    STEP(lab[(G)+6]); STEP(lab[(G)+7]);                                          \
    ISS8(G);                                                                     \
    so += 3328;                                                                  \
    RESCALE(); }

    f32x2 lab[PIPE];
    ISS8(0);  so += 3328;
    ISS8(8);  so += 3328;

    int t = 1;
    for (; t + PIPE - 1 < L; t += PIPE) {
        GROUP8(0);
        GROUP8(8);
    }
    asm volatile("s_waitcnt vmcnt(0)" ::: "memory");   // drain before tail

    for (; t < L; ++t) {
        f32x2 lb = *(const f32x2*)(plane + (size_t)t * EROW);
        STEP(lb);
        RESCALE();
    }
#undef GROUP8
#undef WAITG8
#undef ISS8
#undef ISS
#undef RESCALE
#undef STEP

    __shared__ float A[256];
    A[4 * l + 0] = __builtin_amdgcn_logf(fmaxf(E.x, 1e-38f));
    A[4 * l + 1] = __builtin_amdgcn_logf(fmaxf(O.x, 1e-38f));
    A[4 * l + 2] = __builtin_amdgcn_logf(fmaxf(E.y, 1e-38f));
    A[4 * l + 3] = __builtin_amdgcn_logf(fmaxf(O.y, 1e-38f));
    __syncthreads();
    if (l == 0) {
        const float x1 = A[2 * u_b - 1], x2 = A[2 * u_b];
        const float mx = fmaxf(x1, x2), mn = fminf(x1, x2);
        const float lse2 = mx + __builtin_amdgcn_logf(
            1.f + __builtin_amdgcn_exp2f(mn - mx));
        out[b] = -(LN2 * (lse2 + (float)ksum));
    }
}

extern "C" void kernel_launch(void* const* d_in, const int* in_sizes, int n_in,
                              void* d_out, int out_size, void* d_ws, size_t ws_size,
                              hipStream_t stream) {
    const float* lp      = (const float*)d_in[0];   // [T,B,V] f32
    const int*   targets = (const int*)d_in[1];     // [B,U] i32
    const int*   ilen    = (const int*)d_in[2];     // [B] i32
    const int*   tlen    = (const int*)d_in[3];     // [B] i32
    float* out  = (float*)d_out;                    // [B] f32
    float* etab = (float*)d_ws;                     // B*T*EROW*4 = 13.31 MB

    k_lsm_gather<<<TDIM * BDIM / 4, 256, 0, stream>>>(lp, targets, tlen, etab);
    k_alpha<<<BDIM, 64, 0, stream>>>(etab, targets, ilen, tlen, out);
}

// Round 26
// 69.666 us; speedup vs baseline: 5.5025x; 1.0968x over previous
//
#include <hip/hip_runtime.h>
#include <math.h>

#define TDIM 1000
#define BDIM 32
#define VDIM 1000
#define UDIM 100
#define SDIM 201              // 2*U+1
#define EROW 104              // padded pair-row stride (102 used)
#define LN2   0.6931471805599453f
#define PIPE 16               // software-pipeline depth (t-steps of load prefetch)
// Wave max renormalized to 2^110, rescale every 8 steps (PROVEN R11-R20).
#define SCALE_EXP 110

typedef __attribute__((ext_vector_type(2))) float f32x2;
typedef __attribute__((ext_vector_type(4))) int   i32x4;

// med3(x,0,1): 1-instr clamp; NaN input sanitizes to 0.
__device__ __forceinline__ float med3c(float x) {
    return __builtin_amdgcn_fmed3f(x, 0.f, 1.f);
}

// one DPP butterfly level: v += v[xor-partner] (0-fill outside row)
template <int CTRL>
__device__ __forceinline__ float dppadd(float v) {
    int r = __builtin_amdgcn_update_dpp(
        0, __builtin_bit_cast(int, v), CTRL, 0xf, 0xf, true);
    return v + __builtin_bit_cast(float, r);
}

// ---------------------------------------------------------------------------
// Phase 1 (R20 champion, byte-identical): one wave per (t,b) row. Stores
// PRE-MASKED, PRE-SANITIZED pairs; blank in pair slot 100 (lane-50 pair =
// (blank, 0)). Normal (cached) loads: the gather epilogue re-reads the
// just-streamed row from L1/L2 (R25 measured nt loads -6.4 us for this
// reason).
// ---------------------------------------------------------------------------
__global__ __launch_bounds__(256) void k_lsm_gather(
    const float* __restrict__ lp, const int* __restrict__ targets,
    const int* __restrict__ tlen, float* __restrict__ etab)
{
    const int w = threadIdx.x >> 6, l = threadIdx.x & 63;
    const int row = blockIdx.x * 4 + w;        // row = t*B + b
    const int t = row / BDIM;
    const int b = row - t * BDIM;
    const float* base = lp + (size_t)row * VDIM;
    const float4* p4 = (const float4*)base;    // 250 float4 per row

    float4 v0 = p4[l];
    float4 v1 = p4[64 + l];
    float4 v2 = p4[128 + l];
    float4 v3;
    if (l < 58) v3 = p4[192 + l];
    else        v3 = make_float4(-INFINITY, -INFINITY, -INFINITY, -INFINITY);

    float s = __expf(v0.x) + __expf(v0.y) + __expf(v0.z) + __expf(v0.w)
            + __expf(v1.x) + __expf(v1.y) + __expf(v1.z) + __expf(v1.w)
            + __expf(v2.x) + __expf(v2.y) + __expf(v2.z) + __expf(v2.w)
            + __expf(v3.x) + __expf(v3.y) + __expf(v3.z) + __expf(v3.w);
    s = dppadd<0xB1>(s);    // quad_perm xor1
    s = dppadd<0x4E>(s);    // quad_perm xor2
    s = dppadd<0x141>(s);   // row_half_mirror
    s = dppadd<0x140>(s);   // row_mirror
    s += __shfl_xor(s, 16);
    s += __shfl_xor(s, 32);

    const float inv_s = __builtin_amdgcn_rcpf(s);
    float* erow = etab + (size_t)(b * TDIM + t) * EROW;
    const int Sb = 2 * tlen[b];
    if (l < 50) {
        const int c0 = targets[b * UDIM + 2 * l];
        const int c1 = targets[b * UDIM + 2 * l + 1];
        const float mk1 = (4 * l + 1 <= Sb) ? 1.f : 0.f;
        const float mk3 = (4 * l + 3 <= Sb) ? 1.f : 0.f;
        float2 o;
        o.x = med3c(__expf(base[c0]) * inv_s) * mk1;
        o.y = med3c(__expf(base[c1]) * inv_s) * mk3;
        *(float2*)(erow + 2 * l) = o;
    } else if (l == 50) {
        // slot 100 = blank (readlane source); slot 101 = 0 (state-201 odd pad)
        float2 o;
        o.x = med3c(__expf(base[0]) * inv_s);
        o.y = 0.f;
        *(float2*)(erow + 100) = o;
    }
}

// lane l gets lane l-1's value; lane 0 gets 0.0f (additive identity).
__device__ __forceinline__ float dpp_shr1_zero(float x) {
    int r = __builtin_amdgcn_update_dpp(
        0, __builtin_bit_cast(int, x), 0x138, 0xf, 0xf, true);
    return __builtin_bit_cast(float, r);
}

// one butterfly level of a wave64 max-reduce (p >= 0, so 0-fill is identity)
template <int CTRL>
__device__ __forceinline__ float dppmax(float v) {
    int r = __builtin_amdgcn_update_dpp(
        0, __builtin_bit_cast(int, v), CTRL, 0xf, 0xf, true);
    return fmaxf(v, __builtin_bit_cast(float, r));
}

// ---------------------------------------------------------------------------
// Phase 2 (R20 champion, byte-identical): 1 wave/CU, PIPE=16, readlane
// blank, packed parity state, cadence-8 exact-pow2 rescale.
// ---------------------------------------------------------------------------
__global__ __launch_bounds__(64, 1) void k_alpha(
    const float* __restrict__ etab, const int* __restrict__ targets,
    const int* __restrict__ ilen, const int* __restrict__ tlen,
    float* __restrict__ out)
{
    const int b = blockIdx.x;
    const int l = threadIdx.x;                 // 0..63
    const float* eb = etab + (size_t)b * TDIM * EROW;
    const int eoff = (2 * l <= 100) ? 2 * l : 100;   // lanes>=50 -> blank pair
    const float* plane = eb + eoff;            // per-lane pair base

    f32x2 g = {0.f, 0.f};                      // skip gates (a1f, a3f)
    if (l < 50) {
        const int c0 = targets[b * UDIM + 2 * l];
        const int c1 = targets[b * UDIM + 2 * l + 1];
        g.y = (c1 != c0) ? 1.f : 0.f;
        if (l >= 1) g.x = (c0 != targets[b * UDIM + 2 * l - 1]) ? 1.f : 0.f;
    }

    const int u_b = tlen[b];
    const int Sb  = 2 * u_b;

    f32x2 pr0 = *(const f32x2*)plane;          // pre-sanitized in phase 1
    const float bl0 = __builtin_bit_cast(float,
        __builtin_amdgcn_readlane(__builtin_bit_cast(int, pr0.x), 50));
    const float F = 1e-30f * 0x1p110f;
    f32x2 E, O;
    E.x = (4 * l     <= Sb) ? F : 0.f;
    E.y = (4 * l + 2 <= Sb) ? F : 0.f;
    O.x = (4 * l + 1 <= Sb) ? F : 0.f;
    O.y = (4 * l + 3 <= Sb) ? F : 0.f;
    if (l == 0) {
        E.x = bl0   * 0x1p110f;                // s=0: blank
        O.x = pr0.x * 0x1p110f;                // s=1: first label
    }
    int ksum = -SCALE_EXP;                     // true log2 = log2(stored) + ksum

    int L = ilen[b];
    if (L > TDIM) L = TDIM;

    const unsigned long long ebu = (unsigned long long)eb;
    i32x4 srd;
    srd.x = (int)(ebu & 0xffffffffu);
    srd.y = (int)((ebu >> 32) & 0xffffu);
    srd.z = TDIM * EROW * 4;
    srd.w = 0x00020000;
    const int voff = eoff * 4;                 // per-lane pair byte offset
    int so = EROW * 4;                         // pair soffset (group base)

#define STEP(LAB_) {                                                             \
    const float ebv = __builtin_bit_cast(float,                                  \
        __builtin_amdgcn_readlane(__builtin_bit_cast(int, (LAB_).x), 50));       \
    f32x2 ebp; ebp.x = ebv; ebp.y = ebv;                                         \
    const float pP3 = dpp_shr1_zero(O.y);                                        \
    f32x2 sk; sk.x = pP3; sk.y = O.x;                                            \
    const f32x2 T  = E + O;                                                      \
    const f32x2 ev = (E + sk) * ebp;                                             \
    const f32x2 od = (sk * g + T) * (LAB_);                                      \
    E = ev; O = od; }

#define RESCALE() {                                                              \
    float pm = fmaxf(__builtin_amdgcn_fmed3f(                                    \
        fmaxf(E.x, O.x), fmaxf(E.y, O.y), INFINITY), 0x1p-10f);                  \
    pm = dppmax<0xB1>(pm);   /* quad_perm xor1  */                               \
    pm = dppmax<0x4E>(pm);   /* quad_perm xor2  */                               \
    pm = dppmax<0x141>(pm);  /* row_half_mirror */                               \
    pm = dppmax<0x140>(pm);  /* row_mirror      */                               \
    pm = dppmax<0x142>(pm);  /* row_bcast15    */                                \
    pm = dppmax<0x143>(pm);  /* row_bcast31    */                                \
    const int mb = __builtin_amdgcn_readlane(__builtin_bit_cast(int, pm), 63);   \
    const int ex = (mb >> 23) & 0xff;                                            \
    ksum += ex - (127 + SCALE_EXP);                                              \
    const float sc = __builtin_bit_cast(float, ((254 + SCALE_EXP) - ex) << 23);  \
    f32x2 scv; scv.x = sc; scv.y = sc;                                           \
    E = E * scv; O = O * scv; }

#define ISS(J, OFFP)                                                             \
    asm volatile("buffer_load_dwordx2 %0, %1, %2, %3 offen offset:" OFFP         \
        : "=v"(lab[J]) : "v"(voff), "s"(srd), "s"(so));

#define ISS8(G) \
    ISS((G)+0, "0");    ISS((G)+1, "416");                                       \
    ISS((G)+2, "832");  ISS((G)+3, "1248");                                      \
    ISS((G)+4, "1664"); ISS((G)+5, "2080");                                      \
    ISS((G)+6, "2496"); ISS((G)+7, "2912");

#define WAITG8(J) asm volatile("s_waitcnt vmcnt(8)"                              \
    : "+v"(lab[(J)]),   "+v"(lab[(J)+1]), "+v"(lab[(J)+2]), "+v"(lab[(J)+3]),    \
      "+v"(lab[(J)+4]), "+v"(lab[(J)+5]), "+v"(lab[(J)+6]), "+v"(lab[(J)+7]));

#define GROUP8(G) {                                                              \
    WAITG8(G);                                                                   \
    STEP(lab[(G)+0]); STEP(lab[(G)+1]);                                          \
    STEP(lab[(G)+2]); STEP(lab[(G)+3]);                                          \
    STEP(lab[(G)+4]); STEP(lab[(G)+5]);                                          \
    STEP(lab[(G)+6]); STEP(lab[(G)+7]);                                          \
    ISS8(G);                                                                     \
    so += 3328;                                                                  \
    RESCALE(); }

    f32x2 lab[PIPE];
    ISS8(0);  so += 3328;
    ISS8(8);  so += 3328;

    int t = 1;
    for (; t + PIPE - 1 < L; t += PIPE) {
        GROUP8(0);
        GROUP8(8);
    }
    asm volatile("s_waitcnt vmcnt(0)" ::: "memory");   // drain before tail

    for (; t < L; ++t) {
        f32x2 lb = *(const f32x2*)(plane + (size_t)t * EROW);
        STEP(lb);
        RESCALE();
    }
#undef GROUP8
#undef WAITG8
#undef ISS8
#undef ISS
#undef RESCALE
#undef STEP

    __shared__ float A[256];
    A[4 * l + 0] = __builtin_amdgcn_logf(fmaxf(E.x, 1e-38f));
    A[4 * l + 1] = __builtin_amdgcn_logf(fmaxf(O.x, 1e-38f));
    A[4 * l + 2] = __builtin_amdgcn_logf(fmaxf(E.y, 1e-38f));
    A[4 * l + 3] = __builtin_amdgcn_logf(fmaxf(O.y, 1e-38f));
    __syncthreads();
    if (l == 0) {
        const float x1 = A[2 * u_b - 1], x2 = A[2 * u_b];
        const float mx = fmaxf(x1, x2), mn = fminf(x1, x2);
        const float lse2 = mx + __builtin_amdgcn_logf(
            1.f + __builtin_amdgcn_exp2f(mn - mx));
        out[b] = -(LN2 * (lse2 + (float)ksum));
    }
}

extern "C" void kernel_launch(void* const* d_in, const int* in_sizes, int n_in,
                              void* d_out, int out_size, void* d_ws, size_t ws_size,
                              hipStream_t stream) {
    const float* lp      = (const float*)d_in[0];   // [T,B,V] f32
    const int*   targets = (const int*)d_in[1];     // [B,U] i32
    const int*   ilen    = (const int*)d_in[2];     // [B] i32
    const int*   tlen    = (const int*)d_in[3];     // [B] i32
    float* out  = (float*)d_out;                    // [B] f32
    float* etab = (float*)d_ws;                     // B*T*EROW*4 = 13.31 MB

    k_lsm_gather<<<TDIM * BDIM / 4, 256, 0, stream>>>(lp, targets, tlen, etab);
    k_alpha<<<BDIM, 64, 0, stream>>>(etab, targets, ilen, tlen, out);
}